// Round 10
// baseline (1015.967 us; speedup 1.0000x reference)
//
#include <hip/hip_runtime.h>
#include <hip/hip_bf16.h>
#include <stdint.h>

// CachedOPTAttention: B=4, T=1024, D=2048, H=32, HD=64, causal, idx=0.
// FP32 buffers; bf16-class error budget -> bf16 MFMA math inside.
//
// R12 = R9 pipeline with two REGISTER-CAP fixes (no schedule changes):
//   * QKV: R5's 8-phase 256^2 kernel (refcheck'd correct in R5) with
//     __launch_bounds__(512,1). R5 used (512,2) which hipcc (CUDA semantics:
//     min BLOCKS/CU) turned into a 128-VGPR cap -> acc[8][4] spilled ->
//     1.37GB scratch traffic. (512,1) -> cap 256, need ~200-230.
//   * Attention: R9's QBLK=128 kernel with plain __launch_bounds__(512).
//     The old (512,4) meant 4 blocks/CU -> 64-VGPR cap -> silent spill.
//   * O GEMM stays on the proven gemm128 (512 blocks).
//
// Memory plan (identical to R9):
//   d_out: [0,16) xb (dead after QKV) -> vbt ; [16,32) qb (dead after attn)
//          [32,96) cache f32 (final); O GEMM overwrites [0,32) last.
//   d_ws:  [0,24) WT3 (dead after QKV); [16,32) ctxb; after attn [0,8) WTo.

typedef __hip_bfloat16 bf16;
typedef unsigned short us;
typedef short s16x8 __attribute__((ext_vector_type(8)));
typedef float f32x4 __attribute__((ext_vector_type(4)));

#define T_SEQ   1024
#define D_MODEL 2048

__device__ inline us f2b(float f) {
    bf16 h = __float2bfloat16(f);
    return *(us*)&h;
}

typedef __attribute__((address_space(1))) const void gas_void;
typedef __attribute__((address_space(3))) void las_void;

__device__ inline void gl2lds16(const void* g, void* l) {
    // per-lane global src; LDS dest = wave-uniform base + lane*16
    __builtin_amdgcn_global_load_lds((gas_void*)g, (las_void*)l, 16, 0, 0);
}

#define VMC(n) asm volatile("s_waitcnt vmcnt(" #n ")" ::: "memory")

// ---------------------------------------------------------------------------
// x[4096][2048] f32 -> bf16 (linear)
// ---------------------------------------------------------------------------
__global__ __launch_bounds__(256)
void cvtx_kernel(const float* __restrict__ x, us* __restrict__ xb)
{
    const size_t i = ((size_t)blockIdx.x * 256 + threadIdx.x) * 8;
    float4 a = *(const float4*)(x + i);
    float4 b = *(const float4*)(x + i + 4);
    union { uint4 u; us s[8]; } p;
    p.s[0] = f2b(a.x); p.s[1] = f2b(a.y); p.s[2] = f2b(a.z); p.s[3] = f2b(a.w);
    p.s[4] = f2b(b.x); p.s[5] = f2b(b.y); p.s[6] = f2b(b.z); p.s[7] = f2b(b.w);
    *(uint4*)(xb + i) = p.u;
}

// ---------------------------------------------------------------------------
// W[2048][2048] f32 (k-major) -> Wt + z*2048*2048: bf16 [N][K] (k contiguous).
// ---------------------------------------------------------------------------
__global__ __launch_bounds__(256)
void wtrans_kernel(const float* __restrict__ W0, const float* __restrict__ W1,
                   const float* __restrict__ W2, us* __restrict__ Wt)
{
    __shared__ float tile[64][65];
    const int z = blockIdx.z;
    const float* W = (z == 0) ? W0 : (z == 1) ? W1 : W2;
    us* dst = Wt + (size_t)z * D_MODEL * D_MODEL;

    const int tid = threadIdx.x;
    const int k0 = blockIdx.y * 64, n0 = blockIdx.x * 64;

    const int rr = tid >> 4, cc = (tid & 15) * 4;
    #pragma unroll
    for (int i = 0; i < 4; ++i) {
        float4 v = *(const float4*)(W + (size_t)(k0 + rr + i * 16) * D_MODEL + n0 + cc);
        tile[rr + i * 16][cc]     = v.x;
        tile[rr + i * 16][cc + 1] = v.y;
        tile[rr + i * 16][cc + 2] = v.z;
        tile[rr + i * 16][cc + 3] = v.w;
    }
    __syncthreads();

    const int nr = tid >> 3, kc = (tid & 7) * 8;
    #pragma unroll
    for (int i = 0; i < 2; ++i) {
        const int n = nr + i * 32;
        union { uint4 u; us s[8]; } p;
        #pragma unroll
        for (int j = 0; j < 8; ++j) p.s[j] = f2b(tile[kc + j][n]);
        *(uint4*)(dst + (size_t)(n0 + n) * D_MODEL + k0 + kc) = p.u;
    }
}

// ---------------------------------------------------------------------------
// v2t: cache slot1 f32 [b][t][h*64+d] -> vbT bf16 [b][h][d][t].
// ---------------------------------------------------------------------------
__global__ __launch_bounds__(256)
void v2t_kernel(const float* __restrict__ cache, us* __restrict__ vbt)
{
    __shared__ float tile[64][65];
    const int t0 = blockIdx.x * 64;
    const int h  = blockIdx.y;
    const int b  = blockIdx.z;

    const float* src = cache + ((size_t)(b * 2 + 1) * T_SEQ) * D_MODEL + h * 64;

    const int tid = threadIdx.x;
    const int rr = tid >> 4, cc = (tid & 15) * 4;
    #pragma unroll
    for (int i = 0; i < 4; ++i) {
        float4 v = *(const float4*)(src + (size_t)(t0 + rr + i * 16) * D_MODEL + cc);
        tile[rr + i * 16][cc]     = v.x;
        tile[rr + i * 16][cc + 1] = v.y;
        tile[rr + i * 16][cc + 2] = v.z;
        tile[rr + i * 16][cc + 3] = v.w;
    }
    __syncthreads();

    const int dr = tid >> 3, tc = (tid & 7) * 8;
    #pragma unroll
    for (int i = 0; i < 2; ++i) {
        const int d = dr + i * 32;
        union { uint4 u; us s[8]; } p;
        #pragma unroll
        for (int j = 0; j < 8; ++j) p.s[j] = f2b(tile[tc + j][d]);
        *(uint4*)(vbt + (size_t)((b * 32 + h) * 64 + d) * 1024 + t0 + tc) = p.u;
    }
}

// ---------------------------------------------------------------------------
// 256x256 8-phase GEMM (R5 schedule, refcheck'd; launch_bounds FIXED).
// MODE 3: col routing by n0>>11: 0 -> bf16 qb scaled 1/8 (bias b0),
//         1/2 -> f32 cache slot 0/1 (bias b1/b2).        (QKV GEMM, N=6144)
// vmcnt ledger: see R5 comments - 8 loads/tile, counted vmcnt(4)/vmcnt(2).
// ---------------------------------------------------------------------------
template<int MODE>
__global__ __launch_bounds__(512, 1)
void gemm256p_kernel(const us* __restrict__ A, const us* __restrict__ Bt,
                     const float* __restrict__ b0, const float* __restrict__ b1,
                     const float* __restrict__ b2,
                     float* __restrict__ out0, float* __restrict__ out1,
                     const int* __restrict__ idxp)
{
    __shared__ __align__(16) us As[2 * 16384];
    __shared__ __align__(16) us Bs[2 * 16384];

    const int tid  = threadIdx.x;
    const int wv   = tid >> 6;       // 0..7
    const int lane = tid & 63;
    const int quad = lane >> 4;
    const int l15  = lane & 15;
    const int wm   = wv >> 2;        // 0..1  (M half)
    const int wn   = wv & 3;         // 0..3  (N quarter)
    const int m0   = blockIdx.y * 256;
    const int n0   = blockIdx.x * 256;

    const int srow = wv * 8 + (lane >> 3);
    const int scol = ((lane & 7) ^ ((lane >> 3) & 7)) * 8;   // inverse-swizzled src
    const us* aG = A  + (size_t)(m0 + srow) * D_MODEL + scol;
    const us* bG = Bt + (size_t)(n0 + srow) * D_MODEL + scol;
    us* aD = As + wv * 512;
    us* bD = Bs + wv * 512;

    const int xq = l15 & 7;

    f32x4 acc[8][4];
    #pragma unroll
    for (int mi = 0; mi < 8; ++mi)
        #pragma unroll
        for (int ni = 0; ni < 4; ++ni) acc[mi][ni] = f32x4{0.f, 0.f, 0.f, 0.f};

    #define LDA(BUF, MI, KK) \
        (*(const s16x8*)(As + (BUF)*16384 + (wm*2 + ((MI)>>2))*4096 \
            + (((MI)&3)*16 + l15)*64 + ((((KK)*4 + quad) ^ xq) * 8)))
    #define LDB(BUF, NI, KK) \
        (*(const s16x8*)(Bs + (BUF)*16384 + wn*4096 \
            + ((NI)*16 + l15)*64 + ((((KK)*4 + quad) ^ xq) * 8)))

    #define STAGE_B01(NB, KOF) { gl2lds16(bG + (KOF),               bD + (NB)*16384);          \
                                 gl2lds16(bG + (KOF) +  64*D_MODEL, bD + (NB)*16384 + 4096); }
    #define STAGE_B23(NB, KOF) { gl2lds16(bG + (KOF) + 128*D_MODEL, bD + (NB)*16384 + 8192);  \
                                 gl2lds16(bG + (KOF) + 192*D_MODEL, bD + (NB)*16384 + 12288); }
    #define STAGE_A02(NB, KOF) { gl2lds16(aG + (KOF),               aD + (NB)*16384);          \
                                 gl2lds16(aG + (KOF) + 128*D_MODEL, aD + (NB)*16384 + 8192); }
    #define STAGE_A13(NB, KOF) { gl2lds16(aG + (KOF) +  64*D_MODEL, aD + (NB)*16384 + 4096);  \
                                 gl2lds16(aG + (KOF) + 192*D_MODEL, aD + (NB)*16384 + 12288); }

    STAGE_B01(0, 0); STAGE_B23(0, 0); STAGE_A02(0, 0); STAGE_A13(0, 0);
    VMC(2);
    __builtin_amdgcn_s_barrier();

    #define KTILE(BUF, STG, KOFN, VM2STMT, VM4STMT) do {                          \
        s16x8 aL[4][2], aH[4][2], bF0[2][2], bF1[2][2];                           \
        /* phase 1: miL x niL */                                                  \
        _Pragma("unroll") for (int mi = 0; mi < 4; ++mi)                          \
            _Pragma("unroll") for (int kk = 0; kk < 2; ++kk)                      \
                aL[mi][kk] = LDA(BUF, mi, kk);                                    \
        _Pragma("unroll") for (int ni = 0; ni < 2; ++ni)                          \
            _Pragma("unroll") for (int kk = 0; kk < 2; ++kk)                      \
                bF0[ni][kk] = LDB(BUF, ni, kk);                                   \
        if (STG) STAGE_B01((BUF)^1, KOFN);                                        \
        __builtin_amdgcn_s_barrier();                                             \
        __builtin_amdgcn_s_setprio(1);                                            \
        _Pragma("unroll") for (int kk = 0; kk < 2; ++kk)                          \
            _Pragma("unroll") for (int mi = 0; mi < 4; ++mi)                      \
                _Pragma("unroll") for (int ni = 0; ni < 2; ++ni)                  \
                    acc[mi][ni] = __builtin_amdgcn_mfma_f32_16x16x32_bf16(        \
                        aL[mi][kk], bF0[ni][kk], acc[mi][ni], 0, 0, 0);           \
        __builtin_amdgcn_s_setprio(0);                                            \
        __builtin_amdgcn_s_barrier();                                             \
        /* phase 2: miL x niH */                                                  \
        _Pragma("unroll") for (int ni = 0; ni < 2; ++ni)                          \
            _Pragma("unroll") for (int kk = 0; kk < 2; ++kk)                      \
                bF1[ni][kk] = LDB(BUF, 2 + ni, kk);                               \
        if (STG) STAGE_B23((BUF)^1, KOFN);                                        \
        __builtin_amdgcn_s_barrier();                                             \
        __builtin_amdgcn_s_setprio(1);                                            \
        _Pragma("unroll") for (int kk = 0; kk < 2; ++kk)                          \
            _Pragma("unroll") for (int mi = 0; mi < 4; ++mi)                      \
                _Pragma("unroll") for (int ni = 0; ni < 2; ++ni)                  \
                    acc[mi][2 + ni] = __builtin_amdgcn_mfma_f32_16x16x32_bf16(    \
                        aL[mi][kk], bF1[ni][kk], acc[mi][2 + ni], 0, 0, 0);       \
        __builtin_amdgcn_s_setprio(0);                                            \
        VM2STMT;                                                                  \
        __builtin_amdgcn_s_barrier();                                             \
        /* phase 3: miH x niH */                                                  \
        _Pragma("unroll") for (int mi = 0; mi < 4; ++mi)                          \
            _Pragma("unroll") for (int kk = 0; kk < 2; ++kk)                      \
                aH[mi][kk] = LDA(BUF, 4 + mi, kk);                                \
        if (STG) STAGE_A02((BUF)^1, KOFN);                                        \
        __builtin_amdgcn_s_barrier();                                             \
        __builtin_amdgcn_s_setprio(1);                                            \
        _Pragma("unroll") for (int kk = 0; kk < 2; ++kk)                          \
            _Pragma("unroll") for (int mi = 0; mi < 4; ++mi)                      \
                _Pragma("unroll") for (int ni = 0; ni < 2; ++ni)                  \
                    acc[4 + mi][2 + ni] = __builtin_amdgcn_mfma_f32_16x16x32_bf16(\
                        aH[mi][kk], bF1[ni][kk], acc[4 + mi][2 + ni], 0, 0, 0);   \
        __builtin_amdgcn_s_setprio(0);                                            \
        __builtin_amdgcn_s_barrier();                                             \
        /* phase 4: miH x niL */                                                  \
        if (STG) STAGE_A13((BUF)^1, KOFN);                                        \
        __builtin_amdgcn_s_barrier();                                             \
        __builtin_amdgcn_s_setprio(1);                                            \
        _Pragma("unroll") for (int kk = 0; kk < 2; ++kk)                          \
            _Pragma("unroll") for (int mi = 0; mi < 4; ++mi)                      \
                _Pragma("unroll") for (int ni = 0; ni < 2; ++ni)                  \
                    acc[4 + mi][ni] = __builtin_amdgcn_mfma_f32_16x16x32_bf16(    \
                        aH[mi][kk], bF0[ni][kk], acc[4 + mi][ni], 0, 0, 0);       \
        __builtin_amdgcn_s_setprio(0);                                            \
        VM4STMT;                                                                  \
        __builtin_amdgcn_s_barrier();                                             \
    } while (0)

    for (int t = 0; t < 31; ++t) {
        const int buf = t & 1;
        const int kofn = (t + 1) * 64;
        if (buf == 0) KTILE(0, true, kofn, VMC(4), VMC(2));
        else          KTILE(1, true, kofn, VMC(4), VMC(2));
    }
    KTILE(1, false, 0, VMC(0), VMC(0));

    const int seg = (MODE == 3) ? (n0 >> 11) : 0;
    const float* bias = (MODE == 3) ? (seg == 0 ? b0 : (seg == 1 ? b1 : b2)) : b0;
    const int idx = (MODE == 3 && seg > 0) ? idxp[0] : 0;

    #pragma unroll
    for (int ni = 0; ni < 4; ++ni) {
        const int col = n0 + wn * 64 + ni * 16 + l15;
        const int cl  = col & (D_MODEL - 1);
        const float bv = bias[cl];
        #pragma unroll
        for (int mi = 0; mi < 8; ++mi) {
            #pragma unroll
            for (int r = 0; r < 4; ++r) {
                const int m = m0 + wm * 128 + (mi >> 2) * 64 + (mi & 3) * 16 + quad * 4 + r;
                const float v = acc[mi][ni][r] + bv;
                if (MODE == 0) {
                    out0[(size_t)m * D_MODEL + cl] = v;
                } else {
                    if (seg == 0) {
                        ((us*)out0)[(size_t)m * D_MODEL + cl] = f2b(v * 0.125f);
                    } else {
                        const int b  = m >> 10;
                        const int tt = ((m & 1023) + idx) & 1023;
                        out1[((size_t)(b * 2 + (seg - 1)) * T_SEQ + tt) * D_MODEL + cl] = v;
                    }
                }
            }
        }
    }
    #undef LDA
    #undef LDB
    #undef STAGE_B01
    #undef STAGE_B23
    #undef STAGE_A02
    #undef STAGE_A13
    #undef KTILE
}

// ---------------------------------------------------------------------------
// GEMM (m97 structure, BK=64, R6/R9-proven): O GEMM only.
// ---------------------------------------------------------------------------
__global__ __launch_bounds__(256, 3)
void gemm128_kernel(const us* __restrict__ A, const us* __restrict__ Bt,
                    const float* __restrict__ b0, float* __restrict__ out0)
{
    __shared__ __align__(16) us As[128 * 64];
    __shared__ __align__(16) us Bs[128 * 64];

    const int tid  = threadIdx.x;
    const int wv   = tid >> 6;
    const int lane = tid & 63;
    const int quad = lane >> 4;
    const int l15  = lane & 15;
    const int wm   = wv >> 1;
    const int wn   = wv & 1;

    const int gx  = gridDim.x;
    const int nwg = gx * gridDim.y;
    int bid = blockIdx.y * gx + blockIdx.x;
    bid = (bid & 7) * (nwg >> 3) + (bid >> 3);
    const int m0 = (bid / gx) * 128;
    const int n0 = (bid % gx) * 128;

    const int srow = lane >> 3;
    const int scol = ((lane & 7) ^ srow) * 8;
    const us* aG = A  + (size_t)(m0 + wv * 32 + srow) * D_MODEL + scol;
    const us* bG = Bt + (size_t)(n0 + wv * 32 + srow) * D_MODEL + scol;
    us* aL = As + wv * 32 * 64;
    us* bL = Bs + wv * 32 * 64;

    f32x4 acc[4][4];
    #pragma unroll
    for (int mi = 0; mi < 4; ++mi)
        #pragma unroll
        for (int ni = 0; ni < 4; ++ni) acc[mi][ni] = f32x4{0.f, 0.f, 0.f, 0.f};

    const int xr = l15 & 7;
    #define LDA(MI, KK) (*(const s16x8*)(As + (wm * 64 + (MI) * 16 + l15) * 64 \
                          + ((((KK) * 4 + quad) ^ xr) * 8)))
    #define LDB(NI, KK) (*(const s16x8*)(Bs + (wn * 64 + (NI) * 16 + l15) * 64 \
                          + ((((KK) * 4 + quad) ^ xr) * 8)))

    for (int k0 = 0; k0 < D_MODEL; k0 += 64) {
        #pragma unroll
        for (int g = 0; g < 4; ++g) {
            gl2lds16(aG + k0 + g * 8 * D_MODEL, aL + g * 512);
            gl2lds16(bG + k0 + g * 8 * D_MODEL, bL + g * 512);
        }
        __syncthreads();

        #pragma unroll
        for (int kk = 0; kk < 2; ++kk) {
            s16x8 af[4], bfr[4];
            #pragma unroll
            for (int mi = 0; mi < 4; ++mi) af[mi] = LDA(mi, kk);
            #pragma unroll
            for (int ni = 0; ni < 4; ++ni) bfr[ni] = LDB(ni, kk);
            #pragma unroll
            for (int mi = 0; mi < 4; ++mi)
                #pragma unroll
                for (int ni = 0; ni < 4; ++ni)
                    acc[mi][ni] = __builtin_amdgcn_mfma_f32_16x16x32_bf16(
                        af[mi], bfr[ni], acc[mi][ni], 0, 0, 0);
        }
        __syncthreads();
    }
    #undef LDA
    #undef LDB

    #pragma unroll
    for (int ni = 0; ni < 4; ++ni) {
        const int cl = n0 + wn * 64 + ni * 16 + l15;
        const float bv = b0[cl];
        #pragma unroll
        for (int mi = 0; mi < 4; ++mi) {
            #pragma unroll
            for (int r = 0; r < 4; ++r) {
                const int m = m0 + wm * 64 + mi * 16 + quad * 4 + r;
                out0[(size_t)m * D_MODEL + cl] = acc[mi][ni][r] + bv;
            }
        }
    }
}

// ---------------------------------------------------------------------------
// MFMA flash attention (R9 kernel verbatim; launch_bounds FIX: plain (512) ->
// VGPR cap 256 instead of (512,4)'s 64 -> removes silent spilling).
// ---------------------------------------------------------------------------
#define LDW 72

__global__ __launch_bounds__(512)
void attn_mfma_kernel(const us* __restrict__ q, const float* __restrict__ cache,
                      const us* __restrict__ vbt, us* __restrict__ ctx)
{
    __shared__ __align__(16) us Qs[128 * LDW];   // 18.4 KB; reused as Ps
    __shared__ __align__(16) us Ks[2][64 * LDW]; // 18.4 KB
    __shared__ __align__(16) us Vt[2][64 * 64];  // 16 KB   (total 52.8 KB)

    const int tid  = threadIdx.x;
    const int wave = tid >> 6;          // 0..7
    const int lane = tid & 63;
    const int quad = lane >> 4;
    const int l15  = lane & 15;
    const int xr   = l15 & 7;

    const int bh = blockIdx.x;          // b*32 + h
    const int b  = bh >> 5;
    const int h  = bh & 31;
    const int qt = 7 - blockIdx.y;      // query tile 0..7 (128 rows each)

    const float* kbase = cache + ((size_t)(b * 2 + 0) * T_SEQ) * D_MODEL + h * 64;
    const us* vb_bh = vbt + (size_t)(b * 32 + h) * 65536;   // [64 d][1024 t]

    {
        const int qrow = tid >> 2;
        const int qp   = tid & 3;
        const uint4* qg = (const uint4*)(q + (size_t)(b * T_SEQ + qt * 128 + qrow) * D_MODEL
                                           + h * 64 + qp * 16);
        uint4 q0 = qg[0], q1 = qg[1];
        *(uint4*)(Qs + qrow * LDW + qp * 16)     = q0;
        *(uint4*)(Qs + qrow * LDW + qp * 16 + 8) = q1;
    }

    const int ksrow = tid >> 3;                 // 0..63 (K row)
    const int kp8   = tid & 7;                  // 8-d chunk
    const int vrow  = lane >> 3;                // 0..7
    const int vchk  = (lane & 7) ^ vrow;        // pre-swizzled key-chunk
    const us* vG = vb_bh + (size_t)(wave * 8 + vrow) * 1024 + vchk * 8;

    const int nkt = 2 * qt + 2;

    gl2lds16(vG, (us*)Vt[0] + wave * 512);
    {
        const float4* kg = (const float4*)(kbase + (size_t)ksrow * D_MODEL + kp8 * 8);
        float4 k0 = kg[0], k1 = kg[1];
        union { uint4 u; us s[8]; } p;
        p.s[0] = f2b(k0.x); p.s[1] = f2b(k0.y); p.s[2] = f2b(k0.z); p.s[3] = f2b(k0.w);
        p.s[4] = f2b(k1.x); p.s[5] = f2b(k1.y); p.s[6] = f2b(k1.z); p.s[7] = f2b(k1.w);
        *(uint4*)(&Ks[0][ksrow * LDW + kp8 * 8]) = p.u;
    }
    __syncthreads();

    const s16x8 qf0 = *(const s16x8*)(Qs + (wave * 16 + l15) * LDW + quad * 8);
    const s16x8 qf1 = *(const s16x8*)(Qs + (wave * 16 + l15) * LDW + 32 + quad * 8);

    f32x4 oacc[4];
    #pragma unroll
    for (int t = 0; t < 4; ++t) oacc[t] = f32x4{0.f, 0.f, 0.f, 0.f};
    float m_run[4] = {-1e30f, -1e30f, -1e30f, -1e30f};
    float l_run[4] = {0.f, 0.f, 0.f, 0.f};

    for (int kt = 0; kt < nkt; ++kt) {
        const int buf = kt & 1;
        const bool more = (kt + 1 < nkt);

        float4 nk0, nk1;
        if (more) {
            gl2lds16(vG + (kt + 1) * 64, (us*)Vt[buf ^ 1] + wave * 512);
            const float4* kg = (const float4*)(kbase
                + (size_t)((kt + 1) * 64 + ksrow) * D_MODEL + kp8 * 8);
            nk0 = kg[0]; nk1 = kg[1];
        }

        const int kbr = kt * 64 - qt * 128;
        if (kbr < wave * 16 + 16) {
            const us* kb_ = Ks[buf];
            const us* vb_ = (const us*)Vt[buf];

            f32x4 sacc[4];
            #pragma unroll
            for (int t = 0; t < 4; ++t) sacc[t] = f32x4{0.f, 0.f, 0.f, 0.f};
            #pragma unroll
            for (int t = 0; t < 4; ++t) {
                s16x8 kf0 = *(const s16x8*)(kb_ + (t * 16 + l15) * LDW + quad * 8);
                s16x8 kf1 = *(const s16x8*)(kb_ + (t * 16 + l15) * LDW + 32 + quad * 8);
                sacc[t] = __builtin_amdgcn_mfma_f32_16x16x32_bf16(qf0, kf0, sacc[t], 0, 0, 0);
                sacc[t] = __builtin_amdgcn_mfma_f32_16x16x32_bf16(qf1, kf1, sacc[t], 0, 0, 0);
            }

            if (kbr + 63 > wave * 16) {
                #pragma unroll
                for (int t = 0; t < 4; ++t) {
                    const int keyl = kbr + t * 16 + l15;
                    #pragma unroll
                    for (int r = 0; r < 4; ++r) {
                        if (keyl > wave * 16 + quad * 4 + r) sacc[t][r] = -1e30f;
                    }
                }
            }

            float rmax[4];
            #pragma unroll
            for (int r = 0; r < 4; ++r)
                rmax[r] = fmaxf(fmaxf(sacc[0][r], sacc[1][r]), fmaxf(sacc[2][r], sacc[3][r]));
            #pragma unroll
            for (int off = 1; off < 16; off <<= 1) {
                #pragma unroll
                for (int r = 0; r < 4; ++r) rmax[r] = fmaxf(rmax[r], __shfl_xor(rmax[r], off, 16));
            }
            float alpha[4];
            #pragma unroll
            for (int r = 0; r < 4; ++r) {
                const float mnew = fmaxf(m_run[r], rmax[r]);
                alpha[r] = __expf(m_run[r] - mnew);
                m_run[r] = mnew;
            }
            float rsum[4] = {0.f, 0.f, 0.f, 0.f};
            #pragma unroll
            for (int t = 0; t < 4; ++t) {
                #pragma unroll
                for (int r = 0; r < 4; ++r) {
                    const float p = __expf(sacc[t][r] - m_run[r]);
                    sacc[t][r] = p;
                    rsum[r] += p;
                }
            }
            #pragma unroll
            for (int off = 1; off < 16; off <<= 1) {
                #pragma unroll
                for (int r = 0; r < 4; ++r) rsum[r] += __shfl_xor(rsum[r], off, 16);
            }
            #pragma unroll
            for (int r = 0; r < 4; ++r) l_run[r] = l_run[r] * alpha[r] + rsum[r];
            #pragma unroll
            for (int t = 0; t < 4; ++t) {
                #pragma unroll
                for (int r = 0; r < 4; ++r) oacc[t][r] *= alpha[r];
            }

            #pragma unroll
            for (int t = 0; t < 4; ++t) {
                #pragma unroll
                for (int r = 0; r < 4; ++r)
                    Qs[(wave * 16 + quad * 4 + r) * LDW + t * 16 + l15] = f2b(sacc[t][r]);
            }

            s16x8 pf0 = *(const s16x8*)(Qs + (wave * 16 + l15) * LDW + quad * 8);
            s16x8 pf1 = *(const s16x8*)(Qs + (wave * 16 + l15) * LDW + 32 + quad * 8);
            #pragma unroll
            for (int t = 0; t < 4; ++t) {
                s16x8 vf0 = *(const s16x8*)(vb_ + (t * 16 + l15) * 64 + ((quad ^ xr) * 8));
                s16x8 vf1 = *(const s16x8*)(vb_ + (t * 16 + l15) * 64 + (((4 + quad) ^ xr) * 8));
                oacc[t] = __builtin_amdgcn_mfma_f32_16x16x32_bf16(pf0, vf0, oacc[t], 0, 0, 0);
                oacc[t] = __builtin_amdgcn_mfma_f32_16x16x32_bf16(pf1, vf1, oacc[t], 0, 0, 0);
            }
        }

        if (more) {
            union { uint4 u; us s[8]; } p;
            p.s[0] = f2b(nk0.x); p.s[1] = f2b(nk0.y); p.s[2] = f2b(nk0.z); p.s[3] = f2b(nk0.w);
            p.s[4] = f2b(nk1.x); p.s[5] = f2b(nk1.y); p.s[6] = f2b(nk1.z); p.s[7] = f2b(nk1.w);
            *(uint4*)(&Ks[buf ^ 1][ksrow * LDW + kp8 * 8]) = p.u;
        }
        __syncthreads();
    }

    float invl[4];
    #pragma unroll
    for (int r = 0; r < 4; ++r) invl[r] = 1.0f / l_run[r];
    #pragma unroll
    for (int r = 0; r < 4; ++r) {
        const int qrow = qt * 128 + wave * 16 + quad * 4 + r;
        us* orow = ctx + (size_t)(b * T_SEQ + qrow) * D_MODEL + h * 64;
        #pragma unroll
        for (int t = 0; t < 4; ++t) orow[t * 16 + l15] = f2b(oacc[t][r] * invl[r]);
    }
}

// ---------------------------------------------------------------------------
extern "C" void kernel_launch(void* const* d_in, const int* in_sizes, int n_in,
                              void* d_out, int out_size, void* d_ws, size_t ws_size,
                              hipStream_t stream)
{
    const float* x    = (const float*)d_in[0];
    const int*   idxp = (const int*)d_in[3];
    const float* Wq   = (const float*)d_in[4];
    const float* bq   = (const float*)d_in[5];
    const float* Wk   = (const float*)d_in[6];
    const float* bk   = (const float*)d_in[7];
    const float* Wv   = (const float*)d_in[8];
    const float* bv   = (const float*)d_in[9];
    const float* Wo   = (const float*)d_in[10];
    const float* bo   = (const float*)d_in[11];

    float* out      = (float*)d_out;
    us*    xb       = (us*)d_out;                                   // [0,16MB)
    us*    vbt      = (us*)d_out;                                   // [0,16MB) after QKV
    us*    qb       = (us*)d_out + (size_t)8 * 1024 * 1024;         // [16,32MB)
    float* cacheOut = out + (size_t)4 * T_SEQ * D_MODEL;            // [32,96MB)

    us* WT3  = (us*)d_ws;                                           // [0,24MB)
    us* ctxb = (us*)d_ws + (size_t)8 * 1024 * 1024;                 // [16,32MB) after QKV
    us* WTo  = (us*)d_ws;                                           // [0,8MB)   after attn

    const dim3 tb(256);

    cvtx_kernel<<<dim3(4096), tb, 0, stream>>>(x, xb);
    wtrans_kernel<<<dim3(32, 32, 3), tb, 0, stream>>>(Wq, Wk, Wv, WT3);

    // fused QKV: N = 6144, 8-phase 256^2 tiles -> 24 x 16 = 384 blocks
    gemm256p_kernel<3><<<dim3(24, 16), dim3(512), 0, stream>>>(
        xb, WT3, bq, bk, bv, (float*)qb, cacheOut, idxp);

    // cache slot1 f32 -> vbT bf16 (coalesced LDS-tiled transpose)
    v2t_kernel<<<dim3(16, 32, 4), tb, 0, stream>>>(cacheOut, vbt);

    attn_mfma_kernel<<<dim3(128, 8), dim3(512), 0, stream>>>(qb, cacheOut, vbt, ctxb);

    wtrans_kernel<<<dim3(32, 32, 1), tb, 0, stream>>>(Wo, Wo, Wo, WTo);

    // O GEMM: N = 2048 -> 16 x 32 = 512 blocks
    gemm128_kernel<<<dim3(16, 32), tb, 0, stream>>>(ctxb, WTo, bo, out);
}